// Round 3
// baseline (2923.922 us; speedup 1.0000x reference)
//
#include <hip/hip_runtime.h>

#define N_NODES   100000
#define N_EDGES   800000
#define N_ETYPES  5
#define IN_DIM    23
#define HID_DIM   128
#define OUT_DIM   64
#define NUM_GRAPHS 64
#define NBKT      391                   // ceil(100000/256) dst buckets of 256 nodes
#define PBLK      125                   // partition blocks per etype
#define CHUNK     6400                  // edges per partition block (125*6400 = 800000)
#define PN        (N_ETYPES*NBKT*PBLK)  // 244,375 histogram entries
#define SCAN_NBLK ((PN + 1023) / 1024)  // 239
#define TOT_EDGES (N_ETYPES*N_EDGES)    // 4,000,000

__device__ __forceinline__ unsigned short f2bf(float x) {
    unsigned u = __float_as_uint(x);
    unsigned r = (u + 0x7FFFu + ((u >> 16) & 1u)) >> 16;   // RNE
    return (unsigned short)r;
}
__device__ __forceinline__ float bf2f(unsigned short h) {
    return __uint_as_float(((unsigned)h) << 16);
}

// ---------------- feat -> bf16 table ----------------
__global__ __launch_bounds__(256) void cvt_feat_k(const float* __restrict__ feat,
                                                  unsigned short* __restrict__ fb) {
    int i = blockIdx.x * 256 + threadIdx.x;
    if (i < N_NODES * IN_DIM) fb[i] = f2bf(feat[i]);
}

// ---------------- partition pass 1: per-block bucket histogram ----------------
__global__ __launch_bounds__(256) void part1_k(const int* __restrict__ dst,
                                               int* __restrict__ hp) {
    __shared__ int hist[NBKT];
    int e = blockIdx.y, blk = blockIdx.x, t = threadIdx.x;
    for (int b = t; b < NBKT; b += 256) hist[b] = 0;
    __syncthreads();
    const int* dp = dst + e * N_EDGES + blk * CHUNK;
    for (int k = t; k < CHUNK; k += 256) atomicAdd(&hist[dp[k] >> 8], 1);
    __syncthreads();
    for (int b = t; b < NBKT; b += 256) hp[(e * NBKT + b) * PBLK + blk] = hist[b];
}

// ---------------- exclusive scan over 244,375 ----------------
__global__ __launch_bounds__(256) void scan1_k(const int* __restrict__ in,
                                               int* __restrict__ out,
                                               int* __restrict__ bsum) {
    __shared__ int ls[256];
    int t = threadIdx.x;
    int base = blockIdx.x * 1024 + t * 4;
    int v[4]; int s = 0;
    for (int j = 0; j < 4; j++) { int i = base + j; v[j] = (i < PN) ? in[i] : 0; s += v[j]; }
    ls[t] = s; __syncthreads();
    for (int o = 1; o < 256; o <<= 1) {
        int x = (t >= o) ? ls[t - o] : 0;
        __syncthreads();
        ls[t] += x;
        __syncthreads();
    }
    int run = (t > 0) ? ls[t - 1] : 0;
    if (t == 255) bsum[blockIdx.x] = ls[255];
    for (int j = 0; j < 4; j++) { int i = base + j; if (i < PN) out[i] = run; run += v[j]; }
}

__global__ __launch_bounds__(256) void scan2_k(int* __restrict__ bsum) {
    __shared__ int ls[256];
    int t = threadIdx.x;
    int v = (t < SCAN_NBLK) ? bsum[t] : 0;
    ls[t] = v; __syncthreads();
    for (int o = 1; o < 256; o <<= 1) {
        int x = (t >= o) ? ls[t - o] : 0;
        __syncthreads();
        ls[t] += x;
        __syncthreads();
    }
    if (t < SCAN_NBLK) bsum[t] = (t > 0) ? ls[t - 1] : 0;
}

__global__ __launch_bounds__(256) void scan3_k(int* __restrict__ off,
                                               const int* __restrict__ bsum) {
    int i = blockIdx.x * 256 + threadIdx.x;
    if (i < PN) off[i] += bsum[i >> 10];
}

// ---------------- partition pass 2: blocked contiguous scatter ----------------
__global__ __launch_bounds__(256) void part2_k(const int* __restrict__ src,
                                               const int* __restrict__ dst,
                                               const int* __restrict__ off,
                                               unsigned* __restrict__ ep) {
    __shared__ int cur[NBKT];
    int e = blockIdx.y, blk = blockIdx.x, t = threadIdx.x;
    for (int b = t; b < NBKT; b += 256) cur[b] = off[(e * NBKT + b) * PBLK + blk];
    __syncthreads();
    const int* dp = dst + e * N_EDGES + blk * CHUNK;
    const int* sp = src + e * N_EDGES + blk * CHUNK;
    for (int k = t; k < CHUNK; k += 256) {
        int d = dp[k], s = sp[k];
        int b = d >> 8;
        int pos = atomicAdd(&cur[b], 1);
        ep[pos] = (unsigned)s | ((unsigned)(d & 255) << 24);
    }
}

// ---------------- layer1 push-aggregate: LDS acc per 256-node bucket ----------
// 8 groups x 32 lanes; fuses degree count -> INV; writes scaled AGG1.
__global__ __launch_bounds__(256) void agg1_k(const int* __restrict__ off,
                                              const unsigned* __restrict__ ep,
                                              const unsigned short* __restrict__ fb,
                                              float* __restrict__ inv,
                                              float* __restrict__ agg1) {
    __shared__ float acc[256 * IN_DIM];
    __shared__ int cnti[256];
    __shared__ float invl[256];
    int e = blockIdx.y, b = blockIdx.x, t = threadIdx.x;
    for (int j = t; j < 256 * IN_DIM; j += 256) acc[j] = 0.f;
    cnti[t] = 0;
    __syncthreads();
    int lin = (e * NBKT + b) * PBLK;
    int S = off[lin];
    int E = (lin == (PN - PBLK)) ? TOT_EDGES : off[lin + PBLK];
    int lane = t & 31, g = t >> 5;
    for (int i = S + g; i < E; i += 8) {
        unsigned rec = ep[i];
        int s  = rec & 0xFFFFFF;
        int dl = rec >> 24;
        if (lane < IN_DIM)
            atomicAdd(&acc[dl * IN_DIM + lane], bf2f(fb[s * IN_DIM + lane]));
        else if (lane == 31)
            atomicAdd(&cnti[dl], 1);
    }
    __syncthreads();
    {
        int gn = b * 256 + t;
        float iv = 1.f / (float)(cnti[t] + 1);
        invl[t] = iv;
        if (gn < N_NODES) inv[e * N_NODES + gn] = iv;
    }
    __syncthreads();
    for (int j = t; j < 256 * IN_DIM; j += 256) {
        int dl = j / IN_DIM, d = j - dl * IN_DIM;
        int gn = b * 256 + dl;
        if (gn < N_NODES) agg1[(e * N_NODES + gn) * IN_DIM + d] = acc[j] * invl[dl];
    }
}

// ---------------- layer1 GEMM -> H1 (bf16 out) ----------------
__global__ __launch_bounds__(256) void gemm1_k(const float* __restrict__ feat,
                                               const float* __restrict__ agg1,
                                               const float* __restrict__ inv,
                                               const float* __restrict__ W1,
                                               const float* __restrict__ b1,
                                               unsigned short* __restrict__ h1b) {
    __shared__ float xs[128 * 25];
    __shared__ float wl[IN_DIM * HID_DIM];
    int t = threadIdx.x;
    int node0 = blockIdx.x * 128;
    int ng = t >> 3;
    int o  = t & 7;
    float acc[4][16];
    for (int i = 0; i < 4; i++)
        for (int j = 0; j < 16; j++) acc[i][j] = 0.f;

    for (int e = 0; e < N_ETYPES; e++) {
        __syncthreads();
        for (int j = t; j < IN_DIM * HID_DIM; j += 256)
            wl[j] = W1[e * IN_DIM * HID_DIM + j];
        for (int j = t; j < 128 * IN_DIM; j += 256) {
            int nl = j / IN_DIM;
            int k  = j - nl * IN_DIM;
            int gn = node0 + nl;
            int cn = gn < N_NODES ? gn : N_NODES - 1;
            xs[nl * 25 + k] = agg1[(e * N_NODES + cn) * IN_DIM + k]
                            + feat[cn * IN_DIM + k] * inv[e * N_NODES + cn];
        }
        __syncthreads();
        for (int j = 0; j < 16; j++) {
            float bb = b1[e * HID_DIM + o * 16 + j];
            for (int i = 0; i < 4; i++) acc[i][j] += bb;
        }
        for (int k = 0; k < IN_DIM; k++) {
            float xv[4];
            for (int i = 0; i < 4; i++) xv[i] = xs[(ng * 4 + i) * 25 + k];
            for (int j4 = 0; j4 < 4; j4++) {
                float4 w = *(const float4*)&wl[k * HID_DIM + o * 16 + j4 * 4];
                for (int i = 0; i < 4; i++) {
                    acc[i][j4 * 4 + 0] += xv[i] * w.x;
                    acc[i][j4 * 4 + 1] += xv[i] * w.y;
                    acc[i][j4 * 4 + 2] += xv[i] * w.z;
                    acc[i][j4 * 4 + 3] += xv[i] * w.w;
                }
            }
        }
    }
    for (int i = 0; i < 4; i++) {
        int gn = node0 + ng * 4 + i;
        if (gn < N_NODES) {
            for (int j4 = 0; j4 < 4; j4++) {
                ushort4 v;
                v.x = f2bf(fmaxf(acc[i][j4 * 4 + 0], 0.f));
                v.y = f2bf(fmaxf(acc[i][j4 * 4 + 1], 0.f));
                v.z = f2bf(fmaxf(acc[i][j4 * 4 + 2], 0.f));
                v.w = f2bf(fmaxf(acc[i][j4 * 4 + 3], 0.f));
                *(ushort4*)&h1b[gn * HID_DIM + o * 16 + j4 * 4] = v;
            }
        }
    }
}

// ---------------- layer2 transform GEMM: t2b = bf16(h1 @ W2[e]) ----------------
__global__ __launch_bounds__(256) void gemm2_k(const unsigned short* __restrict__ h1b,
                                               const float* __restrict__ W2,
                                               unsigned short* __restrict__ t2b, int e) {
    __shared__ float xs[256 * 33];
    __shared__ float wl[32 * OUT_DIM];
    int t = threadIdx.x;
    int node0 = blockIdx.x * 256;
    int ng = t >> 2;
    int q  = t & 3;
    float acc[4][16];
    for (int i = 0; i < 4; i++)
        for (int j = 0; j < 16; j++) acc[i][j] = 0.f;

    for (int kc = 0; kc < 4; kc++) {
        __syncthreads();
        int k0 = kc * 32;
        for (int j = t; j < 32 * OUT_DIM; j += 256)
            wl[j] = W2[e * HID_DIM * OUT_DIM + k0 * OUT_DIM + j];
        for (int j = t; j < 256 * 8; j += 256) {
            int nl = j >> 3;
            int k4 = (j & 7) * 4;
            int gn = node0 + nl;
            int cn = gn < N_NODES ? gn : N_NODES - 1;
            ushort4 hv = *(const ushort4*)&h1b[cn * HID_DIM + k0 + k4];
            xs[nl * 33 + k4 + 0] = bf2f(hv.x);
            xs[nl * 33 + k4 + 1] = bf2f(hv.y);
            xs[nl * 33 + k4 + 2] = bf2f(hv.z);
            xs[nl * 33 + k4 + 3] = bf2f(hv.w);
        }
        __syncthreads();
        for (int kk = 0; kk < 32; kk++) {
            float xv[4];
            for (int i = 0; i < 4; i++) xv[i] = xs[(ng * 4 + i) * 33 + kk];
            for (int j4 = 0; j4 < 4; j4++) {
                float4 w = *(const float4*)&wl[kk * OUT_DIM + q * 16 + j4 * 4];
                for (int i = 0; i < 4; i++) {
                    acc[i][j4 * 4 + 0] += xv[i] * w.x;
                    acc[i][j4 * 4 + 1] += xv[i] * w.y;
                    acc[i][j4 * 4 + 2] += xv[i] * w.z;
                    acc[i][j4 * 4 + 3] += xv[i] * w.w;
                }
            }
        }
    }
    for (int i = 0; i < 4; i++) {
        int gn = node0 + ng * 4 + i;
        if (gn < N_NODES) {
            for (int j4 = 0; j4 < 4; j4++) {
                ushort4 v;
                v.x = f2bf(acc[i][j4 * 4 + 0]);
                v.y = f2bf(acc[i][j4 * 4 + 1]);
                v.z = f2bf(acc[i][j4 * 4 + 2]);
                v.w = f2bf(acc[i][j4 * 4 + 3]);
                *(ushort4*)&t2b[gn * OUT_DIM + q * 16 + j4 * 4] = v;
            }
        }
    }
}

// ---------------- layer2 push-aggregate: 64 KB LDS acc per bucket ----------
// 4 waves x 64 lanes; epilogue adds self term, scales by inv, RMWs ACC2.
__global__ __launch_bounds__(256) void gather2_k(const int* __restrict__ off,
                                                 const unsigned* __restrict__ ep,
                                                 const unsigned short* __restrict__ t2b,
                                                 const float* __restrict__ inv,
                                                 float* __restrict__ acc2, int e) {
    extern __shared__ float acc[];   // 256*64 floats = 64 KB
    int b = blockIdx.x, t = threadIdx.x;
    for (int j = t; j < 256 * OUT_DIM; j += 256) acc[j] = 0.f;
    __syncthreads();
    int lin = (e * NBKT + b) * PBLK;
    int S = off[lin];
    int E = (lin == (PN - PBLK)) ? TOT_EDGES : off[lin + PBLK];
    int lane = t & 63, g = t >> 6;
    for (int i = S + g; i < E; i += 4) {
        unsigned rec = ep[i];
        int s  = rec & 0xFFFFFF;
        int dl = rec >> 24;
        atomicAdd(&acc[dl * OUT_DIM + lane], bf2f(t2b[s * OUT_DIM + lane]));
    }
    __syncthreads();
    for (int j = t; j < 256 * OUT_DIM; j += 256) {
        int dl = j >> 6, d = j & 63;
        int gn = b * 256 + dl;
        if (gn < N_NODES) {
            float iv = inv[e * N_NODES + gn];
            acc2[gn * OUT_DIM + d] += (acc[j] + bf2f(t2b[gn * OUT_DIM + d])) * iv;
        }
    }
}

// ---------------- per-graph mean pool ----------------
__global__ __launch_bounds__(256) void pool_k(const float* __restrict__ acc2,
                                              const int* __restrict__ gid,
                                              float* __restrict__ gsum,
                                              float* __restrict__ gcnt) {
    int t = threadIdx.x;
    int d = t & 63;
    int r = t >> 6;
    int i0 = blockIdx.x * 256;
    float sum = 0.f, cnt = 0.f;
    int cur = -1;
    for (int i = i0 + r; i < i0 + 256 && i < N_NODES; i += 4) {
        int g = gid[i];
        if (g != cur) {
            if (cur >= 0) {
                atomicAdd(&gsum[cur * 64 + d], sum);
                if (d == 0) atomicAdd(&gcnt[cur], cnt);
            }
            cur = g; sum = 0.f; cnt = 0.f;
        }
        sum += acc2[i * 64 + d];
        cnt += 1.f;
    }
    if (cur >= 0) {
        atomicAdd(&gsum[cur * 64 + d], sum);
        if (d == 0) atomicAdd(&gcnt[cur], cnt);
    }
}

__global__ __launch_bounds__(256) void final_k(const float* __restrict__ gsum,
                                               const float* __restrict__ gcnt,
                                               const float* __restrict__ b2,
                                               float* __restrict__ out) {
    int idx = blockIdx.x * 256 + threadIdx.x;
    if (idx >= NUM_GRAPHS * OUT_DIM) return;
    int d = idx & 63;
    float B2 = 0.f;
    for (int e = 0; e < N_ETYPES; e++) B2 += b2[e * OUT_DIM + d];
    float c = gcnt[idx >> 6];
    out[idx] = (gsum[idx] + c * B2) / fmaxf(c, 1.0f);
}

extern "C" void kernel_launch(void* const* d_in, const int* in_sizes, int n_in,
                              void* d_out, int out_size, void* d_ws, size_t ws_size,
                              hipStream_t stream) {
    const float* feat = (const float*)d_in[0];
    const int*   src  = (const int*)d_in[1];
    const int*   dst  = (const int*)d_in[2];
    const int*   gid  = (const int*)d_in[3];
    const float* W1   = (const float*)d_in[4];
    const float* b1   = (const float*)d_in[5];
    const float* W2   = (const float*)d_in[6];
    const float* b2   = (const float*)d_in[7];

    float* ws = (float*)d_ws;
    int*            HP   = (int*)ws;                       // 244,375 (round to 245,000)
    int*            OFFP = (int*)ws + 245000;              // 244,375 (round to 245,000)
    int*            BSUM = (int*)ws + 490000;              // 512
    float*          INV  = ws + 490512;                    // 500,000
    unsigned short* FB   = (unsigned short*)(ws + 990512); // 2.3M bf16 = 1,150,000 f
    unsigned*       EP   = (unsigned*)(ws + 2140512);      // 4,000,000
    float*          AGG1 = ws + 6140512;                   // 11,500,000
    unsigned short* H1B  = (unsigned short*)(ws + 17640512); // 12.8M bf16 = 6,400,000 f
    unsigned short* T2B  = (unsigned short*)(ws + 24040512); // 6.4M bf16 = 3,200,000 f
    float*          ACC2 = ws + 27240512;                  // 6,400,000
    float*          GSUM = ws + 33640512;                  // 4,096
    float*          GCNT = ws + 33644608;                  // 64
    // total 33,644,672 floats = 134.6 MB

    hipMemsetAsync(ACC2, 0, (size_t)(6400000 + 4096 + 64) * sizeof(float), stream);

    cvt_feat_k<<<(N_NODES * IN_DIM + 255) / 256, 256, 0, stream>>>(feat, FB);
    part1_k<<<dim3(PBLK, N_ETYPES), 256, 0, stream>>>(dst, HP);
    scan1_k<<<SCAN_NBLK, 256, 0, stream>>>(HP, OFFP, BSUM);
    scan2_k<<<1, 256, 0, stream>>>(BSUM);
    scan3_k<<<(PN + 255) / 256, 256, 0, stream>>>(OFFP, BSUM);
    part2_k<<<dim3(PBLK, N_ETYPES), 256, 0, stream>>>(src, dst, OFFP, EP);

    agg1_k<<<dim3(NBKT, N_ETYPES), 256, 0, stream>>>(OFFP, EP, FB, INV, AGG1);
    gemm1_k<<<782, 256, 0, stream>>>(feat, AGG1, INV, W1, b1, H1B);

    for (int e = 0; e < N_ETYPES; e++) {
        gemm2_k<<<391, 256, 0, stream>>>(H1B, W2, T2B, e);
        gather2_k<<<NBKT, 256, 65536, stream>>>(OFFP, EP, T2B, INV, ACC2, e);
    }

    pool_k<<<391, 256, 0, stream>>>(ACC2, gid, GSUM, GCNT);
    final_k<<<16, 256, 0, stream>>>(GSUM, GCNT, b2, (float*)d_out);
}

// Round 4
// 918.671 us; speedup vs baseline: 3.1828x; 3.1828x over previous
//
#include <hip/hip_runtime.h>

#define N_NODES   100000
#define N_EDGES   800000
#define N_ETYPES  5
#define IN_DIM    23
#define HID_DIM   128
#define OUT_DIM   64
#define NUM_GRAPHS 64
#define NBKT      391                   // ceil(100000/256) dst buckets of 256 nodes
#define PBLK      125                   // partition blocks per etype
#define CHUNK     6400                  // edges per partition block (125*6400 = 800000)
#define PN        (N_ETYPES*NBKT*PBLK)  // 244,375 histogram entries
#define SCAN_NBLK ((PN + 1023) / 1024)  // 239
#define TOT_EDGES (N_ETYPES*N_EDGES)    // 4,000,000
#define BKT_CAP   3072                  // max edges per (etype,bucket); mean 2048, sigma 45

// NOTE (measured round 3): bulk LDS float atomics are ~3.5 cyc/lane on gfx950 —
// push-aggregation via ds_atomic is 30x slower than pull-gather. All aggregation
// below is atomic-free register accumulation over node-sorted edge lists.

__device__ __forceinline__ unsigned short f2bf(float x) {
    unsigned u = __float_as_uint(x);
    unsigned r = (u + 0x7FFFu + ((u >> 16) & 1u)) >> 16;   // RNE
    return (unsigned short)r;
}
__device__ __forceinline__ float bf2f(unsigned short h) {
    return __uint_as_float(((unsigned)h) << 16);
}

// ---------------- feat -> bf16 table ----------------
__global__ __launch_bounds__(256) void cvt_feat_k(const float* __restrict__ feat,
                                                  unsigned short* __restrict__ fb) {
    int i = blockIdx.x * 256 + threadIdx.x;
    if (i < N_NODES * IN_DIM) fb[i] = f2bf(feat[i]);
}

// ---------------- partition pass 1: per-block bucket histogram ----------------
__global__ __launch_bounds__(256) void part1_k(const int* __restrict__ dst,
                                               int* __restrict__ hp) {
    __shared__ int hist[NBKT];
    int e = blockIdx.y, blk = blockIdx.x, t = threadIdx.x;
    for (int b = t; b < NBKT; b += 256) hist[b] = 0;
    __syncthreads();
    const int* dp = dst + e * N_EDGES + blk * CHUNK;
    for (int k = t; k < CHUNK; k += 256) atomicAdd(&hist[dp[k] >> 8], 1);
    __syncthreads();
    for (int b = t; b < NBKT; b += 256) hp[(e * NBKT + b) * PBLK + blk] = hist[b];
}

// ---------------- exclusive scan over 244,375 ----------------
__global__ __launch_bounds__(256) void scan1_k(const int* __restrict__ in,
                                               int* __restrict__ out,
                                               int* __restrict__ bsum) {
    __shared__ int ls[256];
    int t = threadIdx.x;
    int base = blockIdx.x * 1024 + t * 4;
    int v[4]; int s = 0;
    for (int j = 0; j < 4; j++) { int i = base + j; v[j] = (i < PN) ? in[i] : 0; s += v[j]; }
    ls[t] = s; __syncthreads();
    for (int o = 1; o < 256; o <<= 1) {
        int x = (t >= o) ? ls[t - o] : 0;
        __syncthreads();
        ls[t] += x;
        __syncthreads();
    }
    int run = (t > 0) ? ls[t - 1] : 0;
    if (t == 255) bsum[blockIdx.x] = ls[255];
    for (int j = 0; j < 4; j++) { int i = base + j; if (i < PN) out[i] = run; run += v[j]; }
}

__global__ __launch_bounds__(256) void scan2_k(int* __restrict__ bsum) {
    __shared__ int ls[256];
    int t = threadIdx.x;
    int v = (t < SCAN_NBLK) ? bsum[t] : 0;
    ls[t] = v; __syncthreads();
    for (int o = 1; o < 256; o <<= 1) {
        int x = (t >= o) ? ls[t - o] : 0;
        __syncthreads();
        ls[t] += x;
        __syncthreads();
    }
    if (t < SCAN_NBLK) bsum[t] = (t > 0) ? ls[t - 1] : 0;
}

__global__ __launch_bounds__(256) void scan3_k(int* __restrict__ off,
                                               const int* __restrict__ bsum) {
    int i = blockIdx.x * 256 + threadIdx.x;
    if (i < PN) off[i] += bsum[i >> 10];
}

// ---------------- partition pass 2: blocked contiguous scatter ----------------
__global__ __launch_bounds__(256) void part2_k(const int* __restrict__ src,
                                               const int* __restrict__ dst,
                                               const int* __restrict__ off,
                                               unsigned* __restrict__ ep) {
    __shared__ int cur[NBKT];
    int e = blockIdx.y, blk = blockIdx.x, t = threadIdx.x;
    for (int b = t; b < NBKT; b += 256) cur[b] = off[(e * NBKT + b) * PBLK + blk];
    __syncthreads();
    const int* dp = dst + e * N_EDGES + blk * CHUNK;
    const int* sp = src + e * N_EDGES + blk * CHUNK;
    for (int k = t; k < CHUNK; k += 256) {
        int d = dp[k], s = sp[k];
        int b = d >> 8;
        int pos = atomicAdd(&cur[b], 1);
        ep[pos] = (unsigned)s | ((unsigned)(d & 255) << 24);
    }
}

// ---------------- per-bucket counting sort -> node-sorted CSR + NOFF/DEG/INV ---
__global__ __launch_bounds__(256) void sort_k(const int* __restrict__ off,
                                              const unsigned* __restrict__ ep,
                                              unsigned* __restrict__ csr,
                                              int* __restrict__ noff,
                                              int* __restrict__ degn,
                                              float* __restrict__ inv) {
    __shared__ unsigned recs[BKT_CAP];
    __shared__ int hist[256];
    __shared__ int scn[256];
    __shared__ int curp[256];
    int b = blockIdx.x, e = blockIdx.y, t = threadIdx.x;
    int lin = (e * NBKT + b) * PBLK;
    int S = off[lin];
    int E = (lin == PN - PBLK) ? TOT_EDGES : off[lin + PBLK];
    int cnt = E - S;
    hist[t] = 0;
    __syncthreads();
    for (int i = t; i < cnt; i += 256) {
        unsigned r = ep[S + i];
        recs[i] = r;
        atomicAdd(&hist[r >> 24], 1);
    }
    __syncthreads();
    scn[t] = hist[t];
    __syncthreads();
    for (int o = 1; o < 256; o <<= 1) {
        int x = (t >= o) ? scn[t - o] : 0;
        __syncthreads();
        scn[t] += x;
        __syncthreads();
    }
    int excl = scn[t] - hist[t];
    curp[t] = excl;
    int n = b * 256 + t;
    if (n < N_NODES) {
        noff[e * N_NODES + n] = S + excl;
        degn[e * N_NODES + n] = hist[t];
        inv[e * N_NODES + n]  = 1.f / (float)(hist[t] + 1);
    }
    __syncthreads();
    for (int i = t; i < cnt; i += 256) {
        unsigned r = recs[i];
        int pos = atomicAdd(&curp[r >> 24], 1);
        csr[S + pos] = r & 0xFFFFFFu;
    }
}

// ---------------- layer1 pull-aggregate: AGG1[e,n,:] = inv * sum feat_bf16[src] --
__global__ __launch_bounds__(256) void agg1_k(const int* __restrict__ noff,
                                              const int* __restrict__ degn,
                                              const unsigned* __restrict__ csr,
                                              const unsigned short* __restrict__ fb,
                                              const float* __restrict__ inv,
                                              float* __restrict__ agg1) {
    int e = blockIdx.y;
    int t = threadIdx.x;
    int lane = t & 31;
    int n = blockIdx.x * 8 + (t >> 5);
    int idx = e * N_NODES + n;
    int st = noff[idx];
    int cnt = degn[idx];
    if (lane < IN_DIM) {
        float a = 0.f;
        int k = 0;
        for (; k + 1 < cnt; k += 2) {
            int s0 = csr[st + k];
            int s1 = csr[st + k + 1];
            a += bf2f(fb[s0 * IN_DIM + lane]);
            a += bf2f(fb[s1 * IN_DIM + lane]);
        }
        if (k < cnt) a += bf2f(fb[csr[st + k] * IN_DIM + lane]);
        agg1[idx * IN_DIM + lane] = a * inv[idx];
    }
}

// ---------------- layer1 GEMM -> H1 (bf16 out) ----------------
__global__ __launch_bounds__(256) void gemm1_k(const float* __restrict__ feat,
                                               const float* __restrict__ agg1,
                                               const float* __restrict__ inv,
                                               const float* __restrict__ W1,
                                               const float* __restrict__ b1,
                                               unsigned short* __restrict__ h1b) {
    __shared__ float xs[128 * 25];
    __shared__ float wl[IN_DIM * HID_DIM];
    int t = threadIdx.x;
    int node0 = blockIdx.x * 128;
    int ng = t >> 3;
    int o  = t & 7;
    float acc[4][16];
    for (int i = 0; i < 4; i++)
        for (int j = 0; j < 16; j++) acc[i][j] = 0.f;

    for (int e = 0; e < N_ETYPES; e++) {
        __syncthreads();
        for (int j = t; j < IN_DIM * HID_DIM; j += 256)
            wl[j] = W1[e * IN_DIM * HID_DIM + j];
        for (int j = t; j < 128 * IN_DIM; j += 256) {
            int nl = j / IN_DIM;
            int k  = j - nl * IN_DIM;
            int gn = node0 + nl;
            int cn = gn < N_NODES ? gn : N_NODES - 1;
            xs[nl * 25 + k] = agg1[(e * N_NODES + cn) * IN_DIM + k]
                            + feat[cn * IN_DIM + k] * inv[e * N_NODES + cn];
        }
        __syncthreads();
        for (int j = 0; j < 16; j++) {
            float bb = b1[e * HID_DIM + o * 16 + j];
            for (int i = 0; i < 4; i++) acc[i][j] += bb;
        }
        for (int k = 0; k < IN_DIM; k++) {
            float xv[4];
            for (int i = 0; i < 4; i++) xv[i] = xs[(ng * 4 + i) * 25 + k];
            for (int j4 = 0; j4 < 4; j4++) {
                float4 w = *(const float4*)&wl[k * HID_DIM + o * 16 + j4 * 4];
                for (int i = 0; i < 4; i++) {
                    acc[i][j4 * 4 + 0] += xv[i] * w.x;
                    acc[i][j4 * 4 + 1] += xv[i] * w.y;
                    acc[i][j4 * 4 + 2] += xv[i] * w.z;
                    acc[i][j4 * 4 + 3] += xv[i] * w.w;
                }
            }
        }
    }
    for (int i = 0; i < 4; i++) {
        int gn = node0 + ng * 4 + i;
        if (gn < N_NODES) {
            for (int j4 = 0; j4 < 4; j4++) {
                ushort4 v;
                v.x = f2bf(fmaxf(acc[i][j4 * 4 + 0], 0.f));
                v.y = f2bf(fmaxf(acc[i][j4 * 4 + 1], 0.f));
                v.z = f2bf(fmaxf(acc[i][j4 * 4 + 2], 0.f));
                v.w = f2bf(fmaxf(acc[i][j4 * 4 + 3], 0.f));
                *(ushort4*)&h1b[gn * HID_DIM + o * 16 + j4 * 4] = v;
            }
        }
    }
}

// ---------------- layer2 transform GEMM (grid.y = etype): t2b_e = bf16(h1 @ W2[e])
__global__ __launch_bounds__(256) void gemm2_k(const unsigned short* __restrict__ h1b,
                                               const float* __restrict__ W2,
                                               unsigned short* __restrict__ t2b) {
    __shared__ float xs[256 * 33];
    __shared__ float wl[32 * OUT_DIM];
    int e = blockIdx.y;
    int t = threadIdx.x;
    int node0 = blockIdx.x * 256;
    int ng = t >> 2;
    int q  = t & 3;
    float acc[4][16];
    for (int i = 0; i < 4; i++)
        for (int j = 0; j < 16; j++) acc[i][j] = 0.f;

    for (int kc = 0; kc < 4; kc++) {
        __syncthreads();
        int k0 = kc * 32;
        for (int j = t; j < 32 * OUT_DIM; j += 256)
            wl[j] = W2[e * HID_DIM * OUT_DIM + k0 * OUT_DIM + j];
        for (int j = t; j < 256 * 8; j += 256) {
            int nl = j >> 3;
            int k4 = (j & 7) * 4;
            int gn = node0 + nl;
            int cn = gn < N_NODES ? gn : N_NODES - 1;
            ushort4 hv = *(const ushort4*)&h1b[cn * HID_DIM + k0 + k4];
            xs[nl * 33 + k4 + 0] = bf2f(hv.x);
            xs[nl * 33 + k4 + 1] = bf2f(hv.y);
            xs[nl * 33 + k4 + 2] = bf2f(hv.z);
            xs[nl * 33 + k4 + 3] = bf2f(hv.w);
        }
        __syncthreads();
        for (int kk = 0; kk < 32; kk++) {
            float xv[4];
            for (int i = 0; i < 4; i++) xv[i] = xs[(ng * 4 + i) * 33 + kk];
            for (int j4 = 0; j4 < 4; j4++) {
                float4 w = *(const float4*)&wl[kk * OUT_DIM + q * 16 + j4 * 4];
                for (int i = 0; i < 4; i++) {
                    acc[i][j4 * 4 + 0] += xv[i] * w.x;
                    acc[i][j4 * 4 + 1] += xv[i] * w.y;
                    acc[i][j4 * 4 + 2] += xv[i] * w.z;
                    acc[i][j4 * 4 + 3] += xv[i] * w.w;
                }
            }
        }
    }
    unsigned short* out = t2b + (size_t)e * N_NODES * OUT_DIM;
    for (int i = 0; i < 4; i++) {
        int gn = node0 + ng * 4 + i;
        if (gn < N_NODES) {
            for (int j4 = 0; j4 < 4; j4++) {
                ushort4 v;
                v.x = f2bf(acc[i][j4 * 4 + 0]);
                v.y = f2bf(acc[i][j4 * 4 + 1]);
                v.z = f2bf(acc[i][j4 * 4 + 2]);
                v.w = f2bf(acc[i][j4 * 4 + 3]);
                *(ushort4*)&out[gn * OUT_DIM + q * 16 + j4 * 4] = v;
            }
        }
    }
}

// ---------------- layer2 pull + per-graph pool (all 5 etypes, one dispatch) ----
// Block = bucket of 256 nodes; 16 lanes x ushort4 per node; final node vector
// computed fully in registers; per-graph partials in register slots (gid sorted
// -> <=2 graphs/bucket, 4 slots for margin), LDS tree-reduce, 256 atomics/block.
__global__ __launch_bounds__(256) void gather2_k(const int* __restrict__ noff,
                                                 const int* __restrict__ degn,
                                                 const float* __restrict__ inv,
                                                 const unsigned* __restrict__ csr,
                                                 const unsigned short* __restrict__ t2b,
                                                 const int* __restrict__ gid,
                                                 float* __restrict__ gsum) {
    __shared__ float4 red4[16 * 4 * 16];    // 16 KB: [ng][slot][lane]
    int b = blockIdx.x, t = threadIdx.x;
    int lane = t & 15, ng = t >> 4;
    int g0 = gid[b * 256];
    float4 sa0 = {0,0,0,0}, sa1 = {0,0,0,0}, sa2 = {0,0,0,0}, sa3 = {0,0,0,0};

    for (int pass = 0; pass < 16; pass++) {
        int n = b * 256 + pass * 16 + ng;
        if (n >= N_NODES) break;            // uniform: only last block, whole passes
        float4 f = {0,0,0,0};
        for (int e = 0; e < N_ETYPES; e++) {
            int idx = e * N_NODES + n;
            int st = noff[idx];
            int cnt = degn[idx];
            float iv = inv[idx];
            const unsigned short* base = t2b + (size_t)e * N_NODES * OUT_DIM;
            ushort4 sv = *(const ushort4*)&base[n * OUT_DIM + lane * 4];
            float ax = bf2f(sv.x), ay = bf2f(sv.y), az = bf2f(sv.z), aw = bf2f(sv.w);
            int k = 0;
            for (; k + 1 < cnt; k += 2) {
                int sA = csr[st + k];
                int sB = csr[st + k + 1];
                ushort4 vA = *(const ushort4*)&base[sA * OUT_DIM + lane * 4];
                ushort4 vB = *(const ushort4*)&base[sB * OUT_DIM + lane * 4];
                ax += bf2f(vA.x) + bf2f(vB.x);
                ay += bf2f(vA.y) + bf2f(vB.y);
                az += bf2f(vA.z) + bf2f(vB.z);
                aw += bf2f(vA.w) + bf2f(vB.w);
            }
            if (k < cnt) {
                int sA = csr[st + k];
                ushort4 vA = *(const ushort4*)&base[sA * OUT_DIM + lane * 4];
                ax += bf2f(vA.x); ay += bf2f(vA.y); az += bf2f(vA.z); aw += bf2f(vA.w);
            }
            f.x += iv * ax; f.y += iv * ay; f.z += iv * az; f.w += iv * aw;
        }
        int slot = gid[n] - g0;
        float m0 = (slot == 0) ? 1.f : 0.f;
        float m1 = (slot == 1) ? 1.f : 0.f;
        float m2 = (slot == 2) ? 1.f : 0.f;
        float m3 = (slot == 3) ? 1.f : 0.f;
        sa0.x += m0 * f.x; sa0.y += m0 * f.y; sa0.z += m0 * f.z; sa0.w += m0 * f.w;
        sa1.x += m1 * f.x; sa1.y += m1 * f.y; sa1.z += m1 * f.z; sa1.w += m1 * f.w;
        sa2.x += m2 * f.x; sa2.y += m2 * f.y; sa2.z += m2 * f.z; sa2.w += m2 * f.w;
        sa3.x += m3 * f.x; sa3.y += m3 * f.y; sa3.z += m3 * f.z; sa3.w += m3 * f.w;
        if (slot > 3) {                      // statistically never (graphs ~1563 nodes)
            atomicAdd(&gsum[(g0 + slot) * 64 + lane * 4 + 0], f.x);
            atomicAdd(&gsum[(g0 + slot) * 64 + lane * 4 + 1], f.y);
            atomicAdd(&gsum[(g0 + slot) * 64 + lane * 4 + 2], f.z);
            atomicAdd(&gsum[(g0 + slot) * 64 + lane * 4 + 3], f.w);
        }
    }
    red4[(ng * 4 + 0) * 16 + lane] = sa0;
    red4[(ng * 4 + 1) * 16 + lane] = sa1;
    red4[(ng * 4 + 2) * 16 + lane] = sa2;
    red4[(ng * 4 + 3) * 16 + lane] = sa3;
    __syncthreads();
    const float* red = (const float*)red4;
    int slot = t >> 6, d = t & 63;
    float s = 0.f;
    for (int j = 0; j < 16; j++) s += red[(j * 4 + slot) * 64 + d];
    int g = g0 + slot;
    if (g < NUM_GRAPHS) atomicAdd(&gsum[g * 64 + d], s);
}

// ---------------- per-graph node counts ----------------
__global__ __launch_bounds__(256) void gcnt_k(const int* __restrict__ gid,
                                              float* __restrict__ gcnt) {
    __shared__ int h[NUM_GRAPHS];
    int b = blockIdx.x, t = threadIdx.x;
    if (t < NUM_GRAPHS) h[t] = 0;
    __syncthreads();
    int n = b * 256 + t;
    if (n < N_NODES) atomicAdd(&h[gid[n]], 1);
    __syncthreads();
    if (t < NUM_GRAPHS && h[t] > 0) atomicAdd(&gcnt[t], (float)h[t]);
}

__global__ __launch_bounds__(256) void final_k(const float* __restrict__ gsum,
                                               const float* __restrict__ gcnt,
                                               const float* __restrict__ b2,
                                               float* __restrict__ out) {
    int idx = blockIdx.x * 256 + threadIdx.x;
    if (idx >= NUM_GRAPHS * OUT_DIM) return;
    int d = idx & 63;
    float B2 = 0.f;
    for (int e = 0; e < N_ETYPES; e++) B2 += b2[e * OUT_DIM + d];
    float c = gcnt[idx >> 6];
    out[idx] = (gsum[idx] + c * B2) / fmaxf(c, 1.0f);
}

extern "C" void kernel_launch(void* const* d_in, const int* in_sizes, int n_in,
                              void* d_out, int out_size, void* d_ws, size_t ws_size,
                              hipStream_t stream) {
    const float* feat = (const float*)d_in[0];
    const int*   src  = (const int*)d_in[1];
    const int*   dst  = (const int*)d_in[2];
    const int*   gid  = (const int*)d_in[3];
    const float* W1   = (const float*)d_in[4];
    const float* b1   = (const float*)d_in[5];
    const float* W2   = (const float*)d_in[6];
    const float* b2   = (const float*)d_in[7];

    float* ws = (float*)d_ws;
    int*            HP   = (int*)ws;                         //   244,375 (pad 245,000)
    int*            OFFP = (int*)ws + 245000;                //   244,375 (pad 245,000)
    int*            BSUM = (int*)ws + 490000;                //   512
    float*          INV  = ws + 490512;                      //   500,000
    int*            NOFF = (int*)ws + 990512;                //   500,000
    int*            DEGN = (int*)ws + 1490512;               //   500,000
    unsigned short* FB   = (unsigned short*)(ws + 1990512);  //   2.3M bf16 = 1,150,000 f
    float*          GSUM = ws + 3140512;                     //   4,096
    float*          GCNT = ws + 3144608;                     //   64
    unsigned*       EP   = (unsigned*)(ws + 3145000);        //   4,000,000
    float*          AGG1 = ws + 7145000;                     //  11,500,000 (ends 18,645,000)
    unsigned short* T2B  = (unsigned short*)(ws + 3145000);  //  32M bf16 = 16,000,000 f
                    // T2B aliases EP (dead after sort_k) + AGG1 (dead after gemm1_k)
    unsigned short* H1B  = (unsigned short*)(ws + 19145000); //  12.8M bf16 = 6,400,000 f
    unsigned*       CSR  = (unsigned*)(ws + 25545000);       //   4,000,000
    // total 29,545,000 floats = 118.2 MB

    hipMemsetAsync(GSUM, 0, (size_t)(4096 + 64) * sizeof(float), stream);

    cvt_feat_k<<<(N_NODES * IN_DIM + 255) / 256, 256, 0, stream>>>(feat, FB);
    part1_k<<<dim3(PBLK, N_ETYPES), 256, 0, stream>>>(dst, HP);
    scan1_k<<<SCAN_NBLK, 256, 0, stream>>>(HP, OFFP, BSUM);
    scan2_k<<<1, 256, 0, stream>>>(BSUM);
    scan3_k<<<(PN + 255) / 256, 256, 0, stream>>>(OFFP, BSUM);
    part2_k<<<dim3(PBLK, N_ETYPES), 256, 0, stream>>>(src, dst, OFFP, EP);
    sort_k<<<dim3(NBKT, N_ETYPES), 256, 0, stream>>>(OFFP, EP, CSR, NOFF, DEGN, INV);

    agg1_k<<<dim3(12500, N_ETYPES), 256, 0, stream>>>(NOFF, DEGN, CSR, FB, INV, AGG1);
    gemm1_k<<<782, 256, 0, stream>>>(feat, AGG1, INV, W1, b1, H1B);
    gemm2_k<<<dim3(391, N_ETYPES), 256, 0, stream>>>(H1B, W2, T2B);
    gather2_k<<<NBKT, 256, 0, stream>>>(NOFF, DEGN, INV, CSR, T2B, gid, GSUM);

    gcnt_k<<<391, 256, 0, stream>>>(gid, GCNT);
    final_k<<<16, 256, 0, stream>>>(GSUM, GCNT, b2, (float*)d_out);
}

// Round 5
// 654.283 us; speedup vs baseline: 4.4689x; 1.4041x over previous
//
#include <hip/hip_runtime.h>

#define N_NODES   100000
#define N_EDGES   800000
#define N_ETYPES  5
#define IN_DIM    23
#define FPAD      24                    // feat dims padded to 24 (48 B bf16 rows)
#define HID_DIM   128
#define OUT_DIM   64
#define NUM_GRAPHS 64
#define NBKT      391                   // ceil(100000/256) dst buckets of 256 nodes
#define PBLK      125                   // partition blocks per etype
#define CHUNK     6400                  // edges per partition block (125*6400 = 800000)
#define PN        (N_ETYPES*NBKT*PBLK)  // 244,375 histogram entries
#define SCAN_NBLK ((PN + 1023) / 1024)  // 239
#define TOT_EDGES (N_ETYPES*N_EDGES)    // 4,000,000
#define BKT_CAP   3072                  // max edges per (etype,bucket); mean 2048, sigma 45

// NOTE (measured r3): bulk LDS float atomics ~3.5 cyc/lane on gfx950 — push-aggregation
// via ds_atomic is 30x slower than pull-gather. All aggregation is atomic-free pull.
// NOTE (measured r4): 391-block gather ran at 16.6% occupancy, latency-bound on L3
// row gathers (FETCH 517 MB @ 1.45 TB/s). Grid must be >= ~1500 blocks to hide L3 latency.

__device__ __forceinline__ unsigned short f2bf(float x) {
    unsigned u = __float_as_uint(x);
    unsigned r = (u + 0x7FFFu + ((u >> 16) & 1u)) >> 16;   // RNE
    return (unsigned short)r;
}
__device__ __forceinline__ float bf2f(unsigned short h) {
    return __uint_as_float(((unsigned)h) << 16);
}

// ---------------- feat -> bf16 table, padded to 24 dims ----------------
__global__ __launch_bounds__(256) void cvt_feat_k(const float* __restrict__ feat,
                                                  unsigned short* __restrict__ fb24) {
    int i = blockIdx.x * 256 + threadIdx.x;
    if (i < N_NODES * FPAD) {
        int n = i / FPAD, d = i - n * FPAD;
        fb24[i] = (d < IN_DIM) ? f2bf(feat[n * IN_DIM + d]) : (unsigned short)0;
    }
}

// ---------------- partition pass 1: per-block bucket histogram ----------------
__global__ __launch_bounds__(256) void part1_k(const int* __restrict__ dst,
                                               int* __restrict__ hp) {
    __shared__ int hist[NBKT];
    int e = blockIdx.y, blk = blockIdx.x, t = threadIdx.x;
    for (int b = t; b < NBKT; b += 256) hist[b] = 0;
    __syncthreads();
    const int* dp = dst + e * N_EDGES + blk * CHUNK;
    for (int k = t; k < CHUNK; k += 256) atomicAdd(&hist[dp[k] >> 8], 1);
    __syncthreads();
    for (int b = t; b < NBKT; b += 256) hp[(e * NBKT + b) * PBLK + blk] = hist[b];
}

// ---------------- exclusive scan over 244,375 ----------------
__global__ __launch_bounds__(256) void scan1_k(const int* __restrict__ in,
                                               int* __restrict__ out,
                                               int* __restrict__ bsum) {
    __shared__ int ls[256];
    int t = threadIdx.x;
    int base = blockIdx.x * 1024 + t * 4;
    int v[4]; int s = 0;
    for (int j = 0; j < 4; j++) { int i = base + j; v[j] = (i < PN) ? in[i] : 0; s += v[j]; }
    ls[t] = s; __syncthreads();
    for (int o = 1; o < 256; o <<= 1) {
        int x = (t >= o) ? ls[t - o] : 0;
        __syncthreads();
        ls[t] += x;
        __syncthreads();
    }
    int run = (t > 0) ? ls[t - 1] : 0;
    if (t == 255) bsum[blockIdx.x] = ls[255];
    for (int j = 0; j < 4; j++) { int i = base + j; if (i < PN) out[i] = run; run += v[j]; }
}

__global__ __launch_bounds__(256) void scan2_k(int* __restrict__ bsum) {
    __shared__ int ls[256];
    int t = threadIdx.x;
    int v = (t < SCAN_NBLK) ? bsum[t] : 0;
    ls[t] = v; __syncthreads();
    for (int o = 1; o < 256; o <<= 1) {
        int x = (t >= o) ? ls[t - o] : 0;
        __syncthreads();
        ls[t] += x;
        __syncthreads();
    }
    if (t < SCAN_NBLK) bsum[t] = (t > 0) ? ls[t - 1] : 0;
}

__global__ __launch_bounds__(256) void scan3_k(int* __restrict__ off,
                                               const int* __restrict__ bsum) {
    int i = blockIdx.x * 256 + threadIdx.x;
    if (i < PN) off[i] += bsum[i >> 10];
}

// ---------------- partition pass 2: blocked contiguous scatter ----------------
__global__ __launch_bounds__(256) void part2_k(const int* __restrict__ src,
                                               const int* __restrict__ dst,
                                               const int* __restrict__ off,
                                               unsigned* __restrict__ ep) {
    __shared__ int cur[NBKT];
    int e = blockIdx.y, blk = blockIdx.x, t = threadIdx.x;
    for (int b = t; b < NBKT; b += 256) cur[b] = off[(e * NBKT + b) * PBLK + blk];
    __syncthreads();
    const int* dp = dst + e * N_EDGES + blk * CHUNK;
    const int* sp = src + e * N_EDGES + blk * CHUNK;
    for (int k = t; k < CHUNK; k += 256) {
        int d = dp[k], s = sp[k];
        int b = d >> 8;
        int pos = atomicAdd(&cur[b], 1);
        ep[pos] = (unsigned)s | ((unsigned)(d & 255) << 24);
    }
}

// ---------------- per-bucket counting sort -> node-sorted CSR + NOFF/DEG/INV ---
__global__ __launch_bounds__(256) void sort_k(const int* __restrict__ off,
                                              const unsigned* __restrict__ ep,
                                              unsigned* __restrict__ csr,
                                              int* __restrict__ noff,
                                              int* __restrict__ degn,
                                              float* __restrict__ inv) {
    __shared__ unsigned recs[BKT_CAP];
    __shared__ int hist[256];
    __shared__ int scn[256];
    __shared__ int curp[256];
    int b = blockIdx.x, e = blockIdx.y, t = threadIdx.x;
    int lin = (e * NBKT + b) * PBLK;
    int S = off[lin];
    int E = (lin == PN - PBLK) ? TOT_EDGES : off[lin + PBLK];
    int cnt = E - S;
    hist[t] = 0;
    __syncthreads();
    for (int i = t; i < cnt; i += 256) {
        unsigned r = ep[S + i];
        recs[i] = r;
        atomicAdd(&hist[r >> 24], 1);
    }
    __syncthreads();
    scn[t] = hist[t];
    __syncthreads();
    for (int o = 1; o < 256; o <<= 1) {
        int x = (t >= o) ? scn[t - o] : 0;
        __syncthreads();
        scn[t] += x;
        __syncthreads();
    }
    int excl = scn[t] - hist[t];
    curp[t] = excl;
    int n = b * 256 + t;
    if (n < N_NODES) {
        noff[e * N_NODES + n] = S + excl;
        degn[e * N_NODES + n] = hist[t];
        inv[e * N_NODES + n]  = 1.f / (float)(hist[t] + 1);
    }
    __syncthreads();
    for (int i = t; i < cnt; i += 256) {
        unsigned r = recs[i];
        int pos = atomicAdd(&curp[r >> 24], 1);
        csr[S + pos] = r & 0xFFFFFFu;
    }
}

// ---------------- layer1 pull-aggregate: AGG1[e,n,0:24] = inv * sum fb24[src] ----
// 16 groups x 16 lanes; lanes 0..11 each own 2 dims (ushort2 loads, 48 B rows).
__global__ __launch_bounds__(256) void agg1_k(const int* __restrict__ noff,
                                              const int* __restrict__ degn,
                                              const unsigned* __restrict__ csr,
                                              const unsigned short* __restrict__ fb24,
                                              const float* __restrict__ inv,
                                              float* __restrict__ agg1) {
    int e = blockIdx.y;
    int t = threadIdx.x;
    int lane = t & 15;
    int n = blockIdx.x * 16 + (t >> 4);
    int idx = e * N_NODES + n;
    if (lane >= 12) return;
    int st = noff[idx];
    int cnt = degn[idx];
    float a0 = 0.f, a1 = 0.f;
    int k = 0;
    for (; k + 1 < cnt; k += 2) {
        int s0 = csr[st + k];
        int s1 = csr[st + k + 1];
        ushort2 v0 = *(const ushort2*)&fb24[s0 * FPAD + lane * 2];
        ushort2 v1 = *(const ushort2*)&fb24[s1 * FPAD + lane * 2];
        a0 += bf2f(v0.x) + bf2f(v1.x);
        a1 += bf2f(v0.y) + bf2f(v1.y);
    }
    if (k < cnt) {
        int s0 = csr[st + k];
        ushort2 v0 = *(const ushort2*)&fb24[s0 * FPAD + lane * 2];
        a0 += bf2f(v0.x);
        a1 += bf2f(v0.y);
    }
    float iv = inv[idx];
    float2 o; o.x = a0 * iv; o.y = a1 * iv;
    *(float2*)&agg1[(size_t)idx * FPAD + lane * 2] = o;
}

// ---------------- layer1 GEMM -> H1 (bf16 out); AGG1 has stride 24 ----------------
__global__ __launch_bounds__(256) void gemm1_k(const float* __restrict__ feat,
                                               const float* __restrict__ agg1,
                                               const float* __restrict__ inv,
                                               const float* __restrict__ W1,
                                               const float* __restrict__ b1,
                                               unsigned short* __restrict__ h1b) {
    __shared__ float xs[128 * 25];
    __shared__ float wl[IN_DIM * HID_DIM];
    int t = threadIdx.x;
    int node0 = blockIdx.x * 128;
    int ng = t >> 3;
    int o  = t & 7;
    float acc[4][16];
    for (int i = 0; i < 4; i++)
        for (int j = 0; j < 16; j++) acc[i][j] = 0.f;

    for (int e = 0; e < N_ETYPES; e++) {
        __syncthreads();
        for (int j = t; j < IN_DIM * HID_DIM; j += 256)
            wl[j] = W1[e * IN_DIM * HID_DIM + j];
        for (int j = t; j < 128 * IN_DIM; j += 256) {
            int nl = j / IN_DIM;
            int k  = j - nl * IN_DIM;
            int gn = node0 + nl;
            int cn = gn < N_NODES ? gn : N_NODES - 1;
            xs[nl * 25 + k] = agg1[(size_t)(e * N_NODES + cn) * FPAD + k]
                            + feat[cn * IN_DIM + k] * inv[e * N_NODES + cn];
        }
        __syncthreads();
        for (int j = 0; j < 16; j++) {
            float bb = b1[e * HID_DIM + o * 16 + j];
            for (int i = 0; i < 4; i++) acc[i][j] += bb;
        }
        for (int k = 0; k < IN_DIM; k++) {
            float xv[4];
            for (int i = 0; i < 4; i++) xv[i] = xs[(ng * 4 + i) * 25 + k];
            for (int j4 = 0; j4 < 4; j4++) {
                float4 w = *(const float4*)&wl[k * HID_DIM + o * 16 + j4 * 4];
                for (int i = 0; i < 4; i++) {
                    acc[i][j4 * 4 + 0] += xv[i] * w.x;
                    acc[i][j4 * 4 + 1] += xv[i] * w.y;
                    acc[i][j4 * 4 + 2] += xv[i] * w.z;
                    acc[i][j4 * 4 + 3] += xv[i] * w.w;
                }
            }
        }
    }
    for (int i = 0; i < 4; i++) {
        int gn = node0 + ng * 4 + i;
        if (gn < N_NODES) {
            for (int j4 = 0; j4 < 4; j4++) {
                ushort4 v;
                v.x = f2bf(fmaxf(acc[i][j4 * 4 + 0], 0.f));
                v.y = f2bf(fmaxf(acc[i][j4 * 4 + 1], 0.f));
                v.z = f2bf(fmaxf(acc[i][j4 * 4 + 2], 0.f));
                v.w = f2bf(fmaxf(acc[i][j4 * 4 + 3], 0.f));
                *(ushort4*)&h1b[gn * HID_DIM + o * 16 + j4 * 4] = v;
            }
        }
    }
}

// ---------------- layer2 transform GEMM (grid.y = etype): t2b_e = bf16(h1 @ W2[e])
__global__ __launch_bounds__(256) void gemm2_k(const unsigned short* __restrict__ h1b,
                                               const float* __restrict__ W2,
                                               unsigned short* __restrict__ t2b) {
    __shared__ float xs[256 * 33];
    __shared__ float wl[32 * OUT_DIM];
    int e = blockIdx.y;
    int t = threadIdx.x;
    int node0 = blockIdx.x * 256;
    int ng = t >> 2;
    int q  = t & 3;
    float acc[4][16];
    for (int i = 0; i < 4; i++)
        for (int j = 0; j < 16; j++) acc[i][j] = 0.f;

    for (int kc = 0; kc < 4; kc++) {
        __syncthreads();
        int k0 = kc * 32;
        for (int j = t; j < 32 * OUT_DIM; j += 256)
            wl[j] = W2[e * HID_DIM * OUT_DIM + k0 * OUT_DIM + j];
        for (int j = t; j < 256 * 8; j += 256) {
            int nl = j >> 3;
            int k4 = (j & 7) * 4;
            int gn = node0 + nl;
            int cn = gn < N_NODES ? gn : N_NODES - 1;
            ushort4 hv = *(const ushort4*)&h1b[cn * HID_DIM + k0 + k4];
            xs[nl * 33 + k4 + 0] = bf2f(hv.x);
            xs[nl * 33 + k4 + 1] = bf2f(hv.y);
            xs[nl * 33 + k4 + 2] = bf2f(hv.z);
            xs[nl * 33 + k4 + 3] = bf2f(hv.w);
        }
        __syncthreads();
        for (int kk = 0; kk < 32; kk++) {
            float xv[4];
            for (int i = 0; i < 4; i++) xv[i] = xs[(ng * 4 + i) * 33 + kk];
            for (int j4 = 0; j4 < 4; j4++) {
                float4 w = *(const float4*)&wl[kk * OUT_DIM + q * 16 + j4 * 4];
                for (int i = 0; i < 4; i++) {
                    acc[i][j4 * 4 + 0] += xv[i] * w.x;
                    acc[i][j4 * 4 + 1] += xv[i] * w.y;
                    acc[i][j4 * 4 + 2] += xv[i] * w.z;
                    acc[i][j4 * 4 + 3] += xv[i] * w.w;
                }
            }
        }
    }
    unsigned short* out = t2b + (size_t)e * N_NODES * OUT_DIM;
    for (int i = 0; i < 4; i++) {
        int gn = node0 + ng * 4 + i;
        if (gn < N_NODES) {
            for (int j4 = 0; j4 < 4; j4++) {
                ushort4 v;
                v.x = f2bf(acc[i][j4 * 4 + 0]);
                v.y = f2bf(acc[i][j4 * 4 + 1]);
                v.z = f2bf(acc[i][j4 * 4 + 2]);
                v.w = f2bf(acc[i][j4 * 4 + 3]);
                *(ushort4*)&out[gn * OUT_DIM + q * 16 + j4 * 4] = v;
            }
        }
    }
}

// ---------------- layer2 pull + per-graph pool, quarter-bucket blocks ----------
// grid (NBKT, 4): block = 64 nodes (quarter of a 256-node bucket) x all 5 etypes.
// 16 groups x 16 lanes x ushort4; per-graph partials in 4 register slots (gid
// sorted -> <=2 graphs per 64-node span), LDS tree-reduce, 256 atomics/block.
__global__ __launch_bounds__(256) void gather2_k(const int* __restrict__ noff,
                                                 const int* __restrict__ degn,
                                                 const float* __restrict__ inv,
                                                 const unsigned* __restrict__ csr,
                                                 const unsigned short* __restrict__ t2b,
                                                 const int* __restrict__ gid,
                                                 float* __restrict__ gsum) {
    __shared__ float4 red4[16 * 4 * 16];    // 16 KB: [ng][slot][lane]
    int b = blockIdx.x, qb = blockIdx.y, t = threadIdx.x;
    int lane = t & 15, ng = t >> 4;
    int nbase = b * 256 + qb * 64;
    int gbase = nbase < N_NODES ? nbase : N_NODES - 1;
    int g0 = gid[gbase];
    float4 sa0 = {0,0,0,0}, sa1 = {0,0,0,0}, sa2 = {0,0,0,0}, sa3 = {0,0,0,0};

    for (int pass = 0; pass < 4; pass++) {
        int n = nbase + pass * 16 + ng;
        if (n >= N_NODES) break;
        float4 f = {0,0,0,0};
        for (int e = 0; e < N_ETYPES; e++) {
            int idx = e * N_NODES + n;
            int st = noff[idx];
            int cnt = degn[idx];
            float iv = inv[idx];
            const unsigned short* base = t2b + (size_t)e * N_NODES * OUT_DIM;
            ushort4 sv = *(const ushort4*)&base[n * OUT_DIM + lane * 4];
            float ax = bf2f(sv.x), ay = bf2f(sv.y), az = bf2f(sv.z), aw = bf2f(sv.w);
            int k = 0;
            for (; k + 1 < cnt; k += 2) {
                int sA = csr[st + k];
                int sB = csr[st + k + 1];
                ushort4 vA = *(const ushort4*)&base[sA * OUT_DIM + lane * 4];
                ushort4 vB = *(const ushort4*)&base[sB * OUT_DIM + lane * 4];
                ax += bf2f(vA.x) + bf2f(vB.x);
                ay += bf2f(vA.y) + bf2f(vB.y);
                az += bf2f(vA.z) + bf2f(vB.z);
                aw += bf2f(vA.w) + bf2f(vB.w);
            }
            if (k < cnt) {
                int sA = csr[st + k];
                ushort4 vA = *(const ushort4*)&base[sA * OUT_DIM + lane * 4];
                ax += bf2f(vA.x); ay += bf2f(vA.y); az += bf2f(vA.z); aw += bf2f(vA.w);
            }
            f.x += iv * ax; f.y += iv * ay; f.z += iv * az; f.w += iv * aw;
        }
        int slot = gid[n] - g0;
        float m0 = (slot == 0) ? 1.f : 0.f;
        float m1 = (slot == 1) ? 1.f : 0.f;
        float m2 = (slot == 2) ? 1.f : 0.f;
        float m3 = (slot == 3) ? 1.f : 0.f;
        sa0.x += m0 * f.x; sa0.y += m0 * f.y; sa0.z += m0 * f.z; sa0.w += m0 * f.w;
        sa1.x += m1 * f.x; sa1.y += m1 * f.y; sa1.z += m1 * f.z; sa1.w += m1 * f.w;
        sa2.x += m2 * f.x; sa2.y += m2 * f.y; sa2.z += m2 * f.z; sa2.w += m2 * f.w;
        sa3.x += m3 * f.x; sa3.y += m3 * f.y; sa3.z += m3 * f.z; sa3.w += m3 * f.w;
        if (slot > 3) {                      // statistically never (graphs ~1563 nodes)
            atomicAdd(&gsum[(g0 + slot) * 64 + lane * 4 + 0], f.x);
            atomicAdd(&gsum[(g0 + slot) * 64 + lane * 4 + 1], f.y);
            atomicAdd(&gsum[(g0 + slot) * 64 + lane * 4 + 2], f.z);
            atomicAdd(&gsum[(g0 + slot) * 64 + lane * 4 + 3], f.w);
        }
    }
    red4[(ng * 4 + 0) * 16 + lane] = sa0;
    red4[(ng * 4 + 1) * 16 + lane] = sa1;
    red4[(ng * 4 + 2) * 16 + lane] = sa2;
    red4[(ng * 4 + 3) * 16 + lane] = sa3;
    __syncthreads();
    const float* red = (const float*)red4;
    int slot = t >> 6, d = t & 63;
    float s = 0.f;
    for (int j = 0; j < 16; j++) s += red[(j * 4 + slot) * 64 + d];
    int g = g0 + slot;
    if (g < NUM_GRAPHS) atomicAdd(&gsum[g * 64 + d], s);
}

// ---------------- per-graph node counts ----------------
__global__ __launch_bounds__(256) void gcnt_k(const int* __restrict__ gid,
                                              float* __restrict__ gcnt) {
    __shared__ int h[NUM_GRAPHS];
    int b = blockIdx.x, t = threadIdx.x;
    if (t < NUM_GRAPHS) h[t] = 0;
    __syncthreads();
    int n = b * 256 + t;
    if (n < N_NODES) atomicAdd(&h[gid[n]], 1);
    __syncthreads();
    if (t < NUM_GRAPHS && h[t] > 0) atomicAdd(&gcnt[t], (float)h[t]);
}

__global__ __launch_bounds__(256) void final_k(const float* __restrict__ gsum,
                                               const float* __restrict__ gcnt,
                                               const float* __restrict__ b2,
                                               float* __restrict__ out) {
    int idx = blockIdx.x * 256 + threadIdx.x;
    if (idx >= NUM_GRAPHS * OUT_DIM) return;
    int d = idx & 63;
    float B2 = 0.f;
    for (int e = 0; e < N_ETYPES; e++) B2 += b2[e * OUT_DIM + d];
    float c = gcnt[idx >> 6];
    out[idx] = (gsum[idx] + c * B2) / fmaxf(c, 1.0f);
}

extern "C" void kernel_launch(void* const* d_in, const int* in_sizes, int n_in,
                              void* d_out, int out_size, void* d_ws, size_t ws_size,
                              hipStream_t stream) {
    const float* feat = (const float*)d_in[0];
    const int*   src  = (const int*)d_in[1];
    const int*   dst  = (const int*)d_in[2];
    const int*   gid  = (const int*)d_in[3];
    const float* W1   = (const float*)d_in[4];
    const float* b1   = (const float*)d_in[5];
    const float* W2   = (const float*)d_in[6];
    const float* b2   = (const float*)d_in[7];

    float* ws = (float*)d_ws;
    int*            HP   = (int*)ws;                         //   244,375 (pad 245,000)
    int*            OFFP = (int*)ws + 245000;                //   244,375 (pad 245,000)
    int*            BSUM = (int*)ws + 490000;                //   512
    float*          INV  = ws + 490512;                      //   500,000
    int*            NOFF = (int*)ws + 990512;                //   500,000
    int*            DEGN = (int*)ws + 1490512;               //   500,000
    unsigned short* FB24 = (unsigned short*)(ws + 1990512);  //   2.4M bf16 = 1,200,000 f
    float*          GSUM = ws + 3190512;                     //   4,096
    float*          GCNT = ws + 3194608;                     //   64
    unsigned*       EP   = (unsigned*)(ws + 3195000);        //   4,000,000
    float*          AGG1 = ws + 7195000;                     //  12,000,000 (ends 19,195,000)
    unsigned short* T2B  = (unsigned short*)(ws + 3195000);  //  32M bf16 = 16,000,000 f
                    // T2B aliases EP (dead after sort_k) + AGG1 (dead after gemm1_k)
    unsigned short* H1B  = (unsigned short*)(ws + 19195000); //  12.8M bf16 = 6,400,000 f
    unsigned*       CSR  = (unsigned*)(ws + 25595000);       //   4,000,000
    // total 29,595,000 floats = 118.4 MB

    hipMemsetAsync(GSUM, 0, (size_t)(4096 + 64) * sizeof(float), stream);

    cvt_feat_k<<<(N_NODES * FPAD + 255) / 256, 256, 0, stream>>>(feat, FB24);
    part1_k<<<dim3(PBLK, N_ETYPES), 256, 0, stream>>>(dst, HP);
    scan1_k<<<SCAN_NBLK, 256, 0, stream>>>(HP, OFFP, BSUM);
    scan2_k<<<1, 256, 0, stream>>>(BSUM);
    scan3_k<<<(PN + 255) / 256, 256, 0, stream>>>(OFFP, BSUM);
    part2_k<<<dim3(PBLK, N_ETYPES), 256, 0, stream>>>(src, dst, OFFP, EP);
    sort_k<<<dim3(NBKT, N_ETYPES), 256, 0, stream>>>(OFFP, EP, CSR, NOFF, DEGN, INV);

    agg1_k<<<dim3(6250, N_ETYPES), 256, 0, stream>>>(NOFF, DEGN, CSR, FB24, INV, AGG1);
    gemm1_k<<<782, 256, 0, stream>>>(feat, AGG1, INV, W1, b1, H1B);
    gemm2_k<<<dim3(391, N_ETYPES), 256, 0, stream>>>(H1B, W2, T2B);
    gather2_k<<<dim3(NBKT, 4), 256, 0, stream>>>(NOFF, DEGN, INV, CSR, T2B, gid, GSUM);

    gcnt_k<<<391, 256, 0, stream>>>(gid, GCNT);
    final_k<<<16, 256, 0, stream>>>(GSUM, GCNT, b2, (float*)d_out);
}